// Round 1
// baseline (1251.590 us; speedup 1.0000x reference)
//
#include <hip/hip_runtime.h>

#define B_  4
#define T_  8192
#define E_  1024
#define DK_ 128

__device__ __forceinline__ float dot4(const float4 a, const float4 b, float c) {
    return fmaf(a.x, b.x, fmaf(a.y, b.y, fmaf(a.z, b.z, fmaf(a.w, b.w, c))));
}

// One block per (b, s): 64 queries x 64 keys x d=128 attention with fused QKV projection.
// 512 threads = 8 waves. lane = token index l (0..63); wave w owns m-slice m = 8j + w.
__global__ __launch_bounds__(512, 2)
void dilattn(const float* __restrict__ x_in, const float* __restrict__ P,
             const float* __restrict__ Wk, const float* __restrict__ Wq,
             const float* __restrict__ Wv, float* __restrict__ out)
{
    // 64 KB static LDS, exactly 16384 floats:
    //  A region [0, 8192):    Q rows (64 x 128, col swizzled by +4*row), later reused for V
    //  B region [8192,16384): K^T (128 x 64), later reused for S (64 x 65) + 1/denom (64)
    __shared__ float lds[16384];
    constexpr int A_OFF   = 0;
    constexpr int B_OFF   = 8192;
    constexpr int S_OFF   = 8192;
    constexpr int DEN_OFF = 8192 + 4160;
    const float NORMF = 0.08838834764831845f; // 1/sqrt(128)

    const int tid  = threadIdx.x;
    const int lane = tid & 63;
    const int w    = __builtin_amdgcn_readfirstlane(tid >> 6); // 0..7, wave-uniform
    const int b    = blockIdx.x >> 6;
    const int s    = blockIdx.x & 63;

    // ---------------- Phase 1: QKV projection ----------------
    // token for (l=lane): x_in[b, 128*l + s, :]
    const float* xrow = x_in + ((size_t)b * T_ + 128 * lane + s) * E_;
    const float* wqb  = Wq + (size_t)w * E_;  // wave-uniform base -> scalar loads
    const float* wkb  = Wk + (size_t)w * E_;
    const float* wvb  = Wv + (size_t)w * E_;

    float acc[48];
#pragma unroll
    for (int j = 0; j < 48; ++j) acc[j] = 0.f;

    for (int e = 0; e < E_; e += 4) {
        const float4 x4 = *(const float4*)(xrow + e);
#pragma unroll
        for (int j = 0; j < 16; ++j) {  // Q rows m = 8j + w
            const float4 a = *(const float4*)(wqb + j * (8 * E_) + e);
            acc[j] = dot4(x4, a, acc[j]);
        }
#pragma unroll
        for (int j = 0; j < 16; ++j) {  // K rows m = 8j + w
            const float4 a = *(const float4*)(wkb + j * (8 * E_) + e);
            acc[16 + j] = dot4(x4, a, acc[16 + j]);
        }
#pragma unroll
        for (int j = 0; j < 16; ++j) {  // V rows m = 8j + w
            const float4 a = *(const float4*)(wvb + j * (8 * E_) + e);
            acc[32 + j] = dot4(x4, a, acc[32 + j]);
        }
    }

    // Q[l][m] into A (swizzled), K[l][m] into B transposed as K^T[m][l]
#pragma unroll
    for (int j = 0; j < 16; ++j) {
        const int m = 8 * j + w;
        lds[A_OFF + lane * 128 + ((m + 4 * lane) & 127)] = acc[j];
        lds[B_OFF + m * 64 + lane] = acc[16 + j];
    }
    __syncthreads();

    // ---------------- Phase 2a: S[k][q] = sum_m K[k][m]*Q[q][m]; k = lane ----------------
    float sd[8];
#pragma unroll
    for (int i = 0; i < 8; ++i) sd[i] = 0.f;

    for (int m4 = 0; m4 < 32; ++m4) {
        const float k0 = lds[B_OFF + (4 * m4 + 0) * 64 + lane];
        const float k1 = lds[B_OFF + (4 * m4 + 1) * 64 + lane];
        const float k2 = lds[B_OFF + (4 * m4 + 2) * 64 + lane];
        const float k3 = lds[B_OFF + (4 * m4 + 3) * 64 + lane];
#pragma unroll
        for (int i = 0; i < 8; ++i) {
            const int q = w * 8 + i;                    // wave-uniform -> broadcast read
            const float4 qv = *(const float4*)&lds[A_OFF + q * 128 + ((4 * (m4 + q)) & 127)];
            sd[i] = fmaf(k0, qv.x, fmaf(k1, qv.y, fmaf(k2, qv.z, fmaf(k3, qv.w, sd[i]))));
        }
    }
    __syncthreads();  // all Q/K^T reads done; A and B reusable

    // logits -> S region (mask, pos bias, scale);  V -> A region
#pragma unroll
    for (int i = 0; i < 8; ++i) {
        const int q = w * 8 + i;
        const float pb = P[(size_t)lane * ((size_t)128 * T_) + (size_t)q * 128]; // P[128k,128q]
        const float logit = ((lane >= q ? sd[i] : -10000.f) + pb) * NORMF;
        lds[S_OFF + lane * 65 + q] = logit;
    }
#pragma unroll
    for (int j = 0; j < 16; ++j) {
        const int m = 8 * j + w;
        lds[A_OFF + lane * 128 + ((m + 4 * lane) & 127)] = acc[32 + j]; // V[l][m]
    }
    __syncthreads();

    // ---------------- softmax over k for each column q (wave 0) ----------------
    if (tid < 64) {
        const int q = tid;
        float mx = -3.402823466e38f;
        for (int k = 0; k < 64; ++k) mx = fmaxf(mx, lds[S_OFF + k * 65 + q]);
        float sum = 0.f;
        for (int k = 0; k < 64; ++k) {
            const float ev = __expf(lds[S_OFF + k * 65 + q] - mx);
            lds[S_OFF + k * 65 + q] = ev;
            sum += ev;
        }
        lds[DEN_OFF + q] = 1.0f / sum;
    }
    __syncthreads();

    // ---------------- Phase 2b: O[q][m] = (sum_k p[k][q] * V[k][m]) / denom[q] ----------------
    // q = lane; wave w owns m in [16w, 16w+16)
    float4 o0 = {0,0,0,0}, o1 = {0,0,0,0}, o2 = {0,0,0,0}, o3 = {0,0,0,0};
    for (int k = 0; k < 64; ++k) {
        const float p = lds[S_OFF + k * 65 + lane];
        const int base = A_OFF + k * 128;
        const float4 v0 = *(const float4*)&lds[base + ((16 * w + 0  + 4 * k) & 127)];
        const float4 v1 = *(const float4*)&lds[base + ((16 * w + 4  + 4 * k) & 127)];
        const float4 v2 = *(const float4*)&lds[base + ((16 * w + 8  + 4 * k) & 127)];
        const float4 v3 = *(const float4*)&lds[base + ((16 * w + 12 + 4 * k) & 127)];
        o0.x = fmaf(p, v0.x, o0.x); o0.y = fmaf(p, v0.y, o0.y); o0.z = fmaf(p, v0.z, o0.z); o0.w = fmaf(p, v0.w, o0.w);
        o1.x = fmaf(p, v1.x, o1.x); o1.y = fmaf(p, v1.y, o1.y); o1.z = fmaf(p, v1.z, o1.z); o1.w = fmaf(p, v1.w, o1.w);
        o2.x = fmaf(p, v2.x, o2.x); o2.y = fmaf(p, v2.y, o2.y); o2.z = fmaf(p, v2.z, o2.z); o2.w = fmaf(p, v2.w, o2.w);
        o3.x = fmaf(p, v3.x, o3.x); o3.y = fmaf(p, v3.y, o3.y); o3.z = fmaf(p, v3.z, o3.z); o3.w = fmaf(p, v3.w, o3.w);
    }
    const float inv = lds[DEN_OFF + lane];
    float* orow = out + ((size_t)b * T_ + (size_t)(2 * (s * 64 + lane))) * DK_ + w * 16;
    float4 r0 = {o0.x*inv, o0.y*inv, o0.z*inv, o0.w*inv};
    float4 r1 = {o1.x*inv, o1.y*inv, o1.z*inv, o1.w*inv};
    float4 r2 = {o2.x*inv, o2.y*inv, o2.z*inv, o2.w*inv};
    float4 r3 = {o3.x*inv, o3.y*inv, o3.z*inv, o3.w*inv};
    *(float4*)(orow + 0)  = r0;
    *(float4*)(orow + 4)  = r1;
    *(float4*)(orow + 8)  = r2;
    *(float4*)(orow + 12) = r3;
}

extern "C" void kernel_launch(void* const* d_in, const int* in_sizes, int n_in,
                              void* d_out, int out_size, void* d_ws, size_t ws_size,
                              hipStream_t stream) {
    (void)in_sizes; (void)n_in; (void)d_ws; (void)ws_size;
    const float* x_in = (const float*)d_in[0];
    const float* P    = (const float*)d_in[1];
    const float* Wk   = (const float*)d_in[2];  // NOTE dict order: Wk before Wq
    const float* Wq   = (const float*)d_in[3];
    const float* Wv   = (const float*)d_in[4];
    float* out = (float*)d_out;

    // odd output rows are zero; kernel overwrites the even rows
    hipMemsetAsync(d_out, 0, (size_t)out_size * sizeof(float), stream);
    dilattn<<<dim3(256), dim3(512), 0, stream>>>(x_in, P, Wk, Wq, Wv, out);
}

// Round 3
// 433.939 us; speedup vs baseline: 2.8843x; 2.8843x over previous
//
#include <hip/hip_runtime.h>
#include <hip/hip_bf16.h>

#define B_  4
#define T_  8192
#define E_  1024
#define DK_ 128

typedef __attribute__((ext_vector_type(8))) _Float16 half8;
typedef __attribute__((ext_vector_type(4))) float float4v;

__device__ __forceinline__ half8 cvt8h(float4 a, float4 b) {
    half8 r;
    r[0] = (_Float16)a.x; r[1] = (_Float16)a.y; r[2] = (_Float16)a.z; r[3] = (_Float16)a.w;
    r[4] = (_Float16)b.x; r[5] = (_Float16)b.y; r[6] = (_Float16)b.z; r[7] = (_Float16)b.w;
    return r;
}

// One block per (b, s): fused fp16-MFMA QKV projection + fp32 attention.
// 512 threads = 8 waves. Projection: M=64 tokens, N=384 (Q|K|V), K=1024, BK=64.
// Wave w: M-tile mt=w&3, N-half=w>>2 (12 N-tiles each). 48 fp32 accumulators/wave.
__global__ __launch_bounds__(512, 2)
void dilattn(const float* __restrict__ x_in, const float* __restrict__ P,
             const float* __restrict__ Wk, const float* __restrict__ Wq,
             const float* __restrict__ Wv, float* __restrict__ out)
{
    // 64 KB LDS, aliased:
    //  staging:   xs f16[64][72] (9216 B) | wsm f16[384][72] (55296 B)
    //  attention: A region floats [0,8192) = Q (swizzled) then V; B region [8192,16384) = K^T (rotated) then S
    __shared__ float lds_f[16384];
    ushort* xs  = (ushort*)lds_f;        // [64][72]
    ushort* wsm = xs + 64 * 72;          // [384][72]
    constexpr int A_OFF   = 0;
    constexpr int B_OFF   = 8192;
    constexpr int S_OFF   = 8192;
    constexpr int DEN_OFF = 8192 + 4160;
    const float NORMF = 0.08838834764831845f; // 1/sqrt(128)

    const int tid  = threadIdx.x;
    const int lane = tid & 63;
    const int w    = __builtin_amdgcn_readfirstlane(tid >> 6); // 0..7
    const int b    = blockIdx.x >> 6;
    const int s    = blockIdx.x & 63;

    const int lr   = lane & 15;   // in-tile 16-dim index
    const int lg   = lane >> 4;   // k-group 0..3
    const int mt   = w & 3;       // M-tile
    const int half = w >> 2;      // N-half

    // ------- staging assignment: thread -> (row, 8-float chunk) -------
    const int c8 = tid & 7;       // chunk 0..7 (8 floats each, BK=64)
    const int xr = tid >> 3;      // row 0..63
    const float* xrow = x_in + ((size_t)b * T_ + 128 * xr + s) * E_ + c8 * 8;
    const float* wrow[6];
#pragma unroll
    for (int p = 0; p < 6; ++p) {
        const int r = xr + 64 * p; // N row 0..383: 0-127 Q, 128-255 K, 256-383 V
        const float* base = (r < 128) ? (Wq + (size_t)r * E_)
                          : (r < 256) ? (Wk + (size_t)(r - 128) * E_)
                                      : (Wv + (size_t)(r - 256) * E_);
        wrow[p] = base + c8 * 8;
    }

    float4v acc[12];
#pragma unroll
    for (int j = 0; j < 12; ++j) acc[j] = (float4v){0.f, 0.f, 0.f, 0.f};

    // ---------------- Phase 1: QKV projection via MFMA ----------------
    float4 xa0, xa1, wa0[6], wa1[6];
    // preload iter 0
    xa0 = *(const float4*)(xrow);
    xa1 = *(const float4*)(xrow + 4);
#pragma unroll
    for (int p = 0; p < 6; ++p) {
        wa0[p] = *(const float4*)(wrow[p]);
        wa1[p] = *(const float4*)(wrow[p] + 4);
    }

    for (int ki = 0; ki < 16; ++ki) {
        __syncthreads(); // previous iter's LDS reads complete
        *(half8*)&xs[xr * 72 + c8 * 8] = cvt8h(xa0, xa1);
#pragma unroll
        for (int p = 0; p < 6; ++p)
            *(half8*)&wsm[(xr + 64 * p) * 72 + c8 * 8] = cvt8h(wa0[p], wa1[p]);
        __syncthreads(); // tiles visible

        if (ki < 15) { // issue next iter's globals, overlap with MFMA
            const int k0 = (ki + 1) * 64;
            xa0 = *(const float4*)(xrow + k0);
            xa1 = *(const float4*)(xrow + k0 + 4);
#pragma unroll
            for (int p = 0; p < 6; ++p) {
                wa0[p] = *(const float4*)(wrow[p] + k0);
                wa1[p] = *(const float4*)(wrow[p] + k0 + 4);
            }
        }

#pragma unroll
        for (int kk = 0; kk < 2; ++kk) {
            const half8 afr = *(const half8*)&xs[(mt * 16 + lr) * 72 + kk * 32 + lg * 8];
#pragma unroll
            for (int j = 0; j < 12; ++j) {
                const half8 bfr = *(const half8*)&wsm[((half * 12 + j) * 16 + lr) * 72 + kk * 32 + lg * 8];
                acc[j] = __builtin_amdgcn_mfma_f32_16x16x32_f16(afr, bfr, acc[j], 0, 0, 0);
            }
        }
    }
    __syncthreads(); // last MFMA reads done; staging LDS now dead

    // ------- scatter C fragments: Q -> A region (swizzled), K -> B region (rotated K^T) -------
    // C layout: row l = mt*16 + lg*4 + reg (token), col n = nt*16 + lr (out dim)
    const int rbase = mt * 16 + lg * 4;
#pragma unroll
    for (int j = 0; j < 12; ++j) {
        const int nt = half * 12 + j;
        const int n  = nt * 16 + lr;
        if (nt < 8) {        // Q
#pragma unroll
            for (int r = 0; r < 4; ++r) {
                const int l = rbase + r;
                lds_f[A_OFF + l * 128 + ((n + 4 * l) & 127)] = acc[j][r];
            }
        } else if (nt < 16) { // K^T, rotated by m to avoid write conflicts
            const int m = n - 128;
#pragma unroll
            for (int r = 0; r < 4; ++r) {
                const int l = rbase + r;
                lds_f[B_OFF + m * 64 + ((l + m) & 63)] = acc[j][r];
            }
        } // V tiles (nt>=16) stay in registers until after phase 2a
    }
    __syncthreads();

    // ---------------- Phase 2a: S[k][q] = sum_m K[k][m]*Q[q][m]; k = lane ----------------
    float sd[8];
#pragma unroll
    for (int i = 0; i < 8; ++i) sd[i] = 0.f;

    for (int m4 = 0; m4 < 32; ++m4) {
        const int mm = 4 * m4;
        const float k0 = lds_f[B_OFF + (mm + 0) * 64 + ((lane + mm + 0) & 63)];
        const float k1 = lds_f[B_OFF + (mm + 1) * 64 + ((lane + mm + 1) & 63)];
        const float k2 = lds_f[B_OFF + (mm + 2) * 64 + ((lane + mm + 2) & 63)];
        const float k3 = lds_f[B_OFF + (mm + 3) * 64 + ((lane + mm + 3) & 63)];
#pragma unroll
        for (int i = 0; i < 8; ++i) {
            const int q = w * 8 + i; // wave-uniform -> broadcast read
            const float4 qv = *(const float4*)&lds_f[A_OFF + q * 128 + ((4 * (m4 + q)) & 127)];
            sd[i] = fmaf(k0, qv.x, fmaf(k1, qv.y, fmaf(k2, qv.z, fmaf(k3, qv.w, sd[i]))));
        }
    }
    __syncthreads(); // all Q/K^T reads done; A and B regions reusable

    // logits -> S region (mask, pos bias, scale); V fragments -> A region
#pragma unroll
    for (int i = 0; i < 8; ++i) {
        const int q = w * 8 + i;
        const float pb = P[(size_t)lane * ((size_t)128 * T_) + (size_t)q * 128]; // P[128k,128q]
        const float logit = ((lane >= q ? sd[i] : -10000.f) + pb) * NORMF;
        lds_f[S_OFF + lane * 65 + q] = logit;
    }
    if (half == 1) { // V tiles nt=16..23 live in acc[4..11]
#pragma unroll
        for (int j = 4; j < 12; ++j) {
            const int nt = 12 + j;
            const int m  = nt * 16 + lr - 256; // V column 0..127
#pragma unroll
            for (int r = 0; r < 4; ++r) {
                const int l = rbase + r;
                lds_f[A_OFF + l * 128 + ((m + 4 * l) & 127)] = acc[j][r];
            }
        }
    }
    __syncthreads();

    // ---------------- softmax over k for each column q (wave 0) ----------------
    if (tid < 64) {
        const int q = tid;
        float mx = -3.402823466e38f;
        for (int k = 0; k < 64; ++k) mx = fmaxf(mx, lds_f[S_OFF + k * 65 + q]);
        float sum = 0.f;
        for (int k = 0; k < 64; ++k) {
            const float ev = __expf(lds_f[S_OFF + k * 65 + q] - mx);
            lds_f[S_OFF + k * 65 + q] = ev;
            sum += ev;
        }
        lds_f[DEN_OFF + q] = 1.0f / sum;
    }
    __syncthreads();

    // ---------------- Phase 2b: O[q][m] = (sum_k p[k][q] * V[k][m]) / denom[q] ----------------
    float4 o0 = {0,0,0,0}, o1 = {0,0,0,0}, o2 = {0,0,0,0}, o3 = {0,0,0,0};
    for (int k = 0; k < 64; ++k) {
        const float p = lds_f[S_OFF + k * 65 + lane];
        const int base = A_OFF + k * 128;
        const float4 v0 = *(const float4*)&lds_f[base + ((16 * w + 0  + 4 * k) & 127)];
        const float4 v1 = *(const float4*)&lds_f[base + ((16 * w + 4  + 4 * k) & 127)];
        const float4 v2 = *(const float4*)&lds_f[base + ((16 * w + 8  + 4 * k) & 127)];
        const float4 v3 = *(const float4*)&lds_f[base + ((16 * w + 12 + 4 * k) & 127)];
        o0.x = fmaf(p, v0.x, o0.x); o0.y = fmaf(p, v0.y, o0.y); o0.z = fmaf(p, v0.z, o0.z); o0.w = fmaf(p, v0.w, o0.w);
        o1.x = fmaf(p, v1.x, o1.x); o1.y = fmaf(p, v1.y, o1.y); o1.z = fmaf(p, v1.z, o1.z); o1.w = fmaf(p, v1.w, o1.w);
        o2.x = fmaf(p, v2.x, o2.x); o2.y = fmaf(p, v2.y, o2.y); o2.z = fmaf(p, v2.z, o2.z); o2.w = fmaf(p, v2.w, o2.w);
        o3.x = fmaf(p, v3.x, o3.x); o3.y = fmaf(p, v3.y, o3.y); o3.z = fmaf(p, v3.z, o3.z); o3.w = fmaf(p, v3.w, o3.w);
    }
    const float inv = lds_f[DEN_OFF + lane];
    float* orow = out + ((size_t)b * T_ + (size_t)(2 * (s * 64 + lane))) * DK_ + w * 16;
    float4 r0 = {o0.x*inv, o0.y*inv, o0.z*inv, o0.w*inv};
    float4 r1 = {o1.x*inv, o1.y*inv, o1.z*inv, o1.w*inv};
    float4 r2 = {o2.x*inv, o2.y*inv, o2.z*inv, o2.w*inv};
    float4 r3 = {o3.x*inv, o3.y*inv, o3.z*inv, o3.w*inv};
    *(float4*)(orow + 0)  = r0;
    *(float4*)(orow + 4)  = r1;
    *(float4*)(orow + 8)  = r2;
    *(float4*)(orow + 12) = r3;
}

extern "C" void kernel_launch(void* const* d_in, const int* in_sizes, int n_in,
                              void* d_out, int out_size, void* d_ws, size_t ws_size,
                              hipStream_t stream) {
    (void)in_sizes; (void)n_in; (void)d_ws; (void)ws_size;
    const float* x_in = (const float*)d_in[0];
    const float* P    = (const float*)d_in[1];
    const float* Wk   = (const float*)d_in[2];  // dict order: Wk before Wq
    const float* Wq   = (const float*)d_in[3];
    const float* Wv   = (const float*)d_in[4];
    float* out = (float*)d_out;

    // odd output rows are zero; kernel overwrites the even rows
    hipMemsetAsync(d_out, 0, (size_t)out_size * sizeof(float), stream);
    dilattn<<<dim3(256), dim3(512), 0, stream>>>(x_in, P, Wk, Wq, Wv, out);
}